// Round 14
// baseline (282.542 us; speedup 1.0000x reference)
//
#include <hip/hip_runtime.h>
#include <hip/hip_bf16.h>

#define V_ 50000
#define E_ 100
#define H_ 128
#define B_ 16
#define S_ 4096

typedef unsigned short u16;
typedef unsigned int   u32;
typedef short bf16x8 __attribute__((ext_vector_type(8)));  // 8 bf16 = 4 VGPRs
typedef float f32x4  __attribute__((ext_vector_type(4)));

__device__ __forceinline__ float bf2f(u16 x) {
  return __uint_as_float(((u32)x) << 16);
}
__device__ __forceinline__ u16 f2bf(float x) {
  __hip_bfloat16 b = __float2bfloat16(x);
  return *reinterpret_cast<u16*>(&b);
}
__device__ __forceinline__ float sigm(float x) { return 1.0f / (1.0f + __expf(-x)); }
__device__ __forceinline__ float tanh_f(float x) {
  float e = __expf(2.0f * x);
  return 1.0f - 2.0f / (e + 1.0f);
}

// ---------------------------------------------------------------------------
// Merged prep (R13): embB bf16, W_x/Ucat B-frag swizzles, bxs = bx+bl+br
// (per XMAP), bd = f_r - f_l bias delta.
// ---------------------------------------------------------------------------
#define PREP_N0 (V_ * 128)
#define PREP_N1 65536
#define PREP_N2 163840
#define PREP_N3 640
__global__ __launch_bounds__(256) void prep_all(
    const float* __restrict__ emb, const float* __restrict__ Wx,
    const float* __restrict__ Ul, const float* __restrict__ Ur,
    const float* __restrict__ bl, const float* __restrict__ br,
    const float* __restrict__ bx,
    u16* __restrict__ embB, u16* __restrict__ Bx, u16* __restrict__ Bu,
    float* __restrict__ bxs, float* __restrict__ bd)
{
  int i = blockIdx.x * 256 + threadIdx.x;
  if (i < PREP_N0) {
    int k = i & 127, t = i >> 7;
    embB[i] = (k < E_) ? f2bf(emb[t * E_ + k]) : (u16)0;
    return;
  }
  i -= PREP_N0;
  if (i < PREP_N1) {
    int j = i & 7, l = (i >> 3) & 63, s = (i >> 9) & 3, t = i >> 11;
    int k = s * 32 + (l >> 4) * 8 + j;
    int o = t * 16 + (l & 15);
    Bx[i] = (k < E_) ? f2bf(Wx[o * E_ + k]) : (u16)0;
    return;
  }
  i -= PREP_N1;
  if (i < PREP_N2) {
    int j = i & 7, l = (i >> 3) & 63, s = (i >> 9) & 7, t = i >> 12;
    int k = s * 32 + (l >> 4) * 8 + j;
    int gh = t * 16 + (l & 15);
    float v = (k < 128) ? Ul[gh * 128 + k] : Ur[gh * 128 + (k - 128)];
    Bu[i] = f2bf(v);
    return;
  }
  i -= PREP_N2;
  if (i < 512) {
    int g = i >> 7, hh = i & 127;
    int lg = (g == 0) ? 0 : (g == 1) ? 1 : (g == 2) ? 3 : 4;
    bxs[i] = bx[i] + bl[lg * 128 + hh] + br[lg * 128 + hh];
    return;
  }
  i -= 512;
  if (i < 128) bd[i] = (bl[256 + i] + br[256 + i]) - (bl[128 + i] + br[128 + i]);
}

// ---------------------------------------------------------------------------
// xg GEMM via MFMA + LDS transpose (XLDS=514: conflict-free). Biases folded.
// Epilogue emits level-0 h (bf16) AND c (f32), once per element.
// ---------------------------------------------------------------------------
#define XLDS 514
__global__ __launch_bounds__(512) void xg_mfma(
    const u16* __restrict__ embB, const u16* __restrict__ Bx,
    const float* __restrict__ bxs, const int* __restrict__ seq,
    ushort4* __restrict__ xg, u16* __restrict__ h0, float* __restrict__ c0)
{
  __shared__ u16 lds[32 * XLDS];
  const int w = threadIdx.x >> 6, lane = threadIdx.x & 63;
  const int quad = lane >> 4, l15 = lane & 15;
  const int m0 = blockIdx.x * 32;

  f32x4 acc[2][4];
  #pragma unroll
  for (int r = 0; r < 2; ++r)
    #pragma unroll
    for (int t = 0; t < 4; ++t) acc[r][t] = (f32x4){0.f, 0.f, 0.f, 0.f};

  int tok0 = seq[m0 + l15];
  int tok1 = seq[m0 + 16 + l15];
  const u16* a0p = embB + (size_t)tok0 * 128 + quad * 8;
  const u16* a1p = embB + (size_t)tok1 * 128 + quad * 8;

  #pragma unroll
  for (int s = 0; s < 4; ++s) {
    bf16x8 a0 = *reinterpret_cast<const bf16x8*>(a0p + s * 32);
    bf16x8 a1 = *reinterpret_cast<const bf16x8*>(a1p + s * 32);
    #pragma unroll
    for (int ti = 0; ti < 4; ++ti) {
      int t = w * 4 + ti;
      bf16x8 b = *reinterpret_cast<const bf16x8*>(Bx + ((size_t)(t * 4 + s) * 64 + lane) * 8);
      acc[0][ti] = __builtin_amdgcn_mfma_f32_16x16x32_bf16(a0, b, acc[0][ti], 0, 0, 0);
      acc[1][ti] = __builtin_amdgcn_mfma_f32_16x16x32_bf16(a1, b, acc[1][ti], 0, 0, 0);
    }
  }

  const int g = w >> 1;
  #pragma unroll
  for (int ti = 0; ti < 4; ++ti) {
    int o = (w * 4 + ti) * 16 + l15;
    float bxo = bxs[o];
    int hhw = (w & 1) * 64 + ti * 16 + l15;
    #pragma unroll
    for (int r = 0; r < 2; ++r)
      #pragma unroll
      for (int reg = 0; reg < 4; ++reg) {
        int mrow = r * 16 + quad * 4 + reg;
        lds[mrow * XLDS + hhw * 4 + g] = f2bf(acc[r][ti][reg] + bxo);
      }
  }
  __syncthreads();

  #pragma unroll
  for (int i = 0; i < 8; ++i) {
    int pidx = i * 512 + threadIdx.x;
    int m = pidx >> 7, hh = pidx & 127;
    ushort4 v = *reinterpret_cast<const ushort4*>(&lds[m * XLDS + hh * 4]);
    size_t gm = (size_t)(m0 + m);
    xg[gm * 128 + hh] = v;
    float c = sigm(bf2f(v.x)) * tanh_f(bf2f(v.w));
    float h = sigm(bf2f(v.z)) * tanh_f(c);
    h0[gm * 128 + hh] = f2bf(h);
    c0[gm * 128 + hh] = c;
  }
}

// ---------------------------------------------------------------------------
// Fused level PAIR (l, l+1). Stage 1: 64 rows of level l (Mtile=64, A/c from
// global) -> h/c to LDS ONLY. Stage 2: the 32 level-(l+1) rows whose children
// are exactly this block's stage-1 outputs (A from LDS, stride-136 pattern).
// Stage-2 dep indices load at kernel start; its xg gather issues right after
// the stage-1 K-loop (hidden under the stage-1 epilogue).
// ---------------------------------------------------------------------------
__global__ __launch_bounds__(512) void level_pair(
    const ushort4* __restrict__ xg4,
    const int* __restrict__ deprow1, const int* __restrict__ deprow2,
    const u16* __restrict__ Bu, const float* __restrict__ bd,
    const u16* __restrict__ hPrev, const float* __restrict__ cPrev,
    u16* __restrict__ hOut2, float* __restrict__ cOut2, int n, int ln2n)
{
  __shared__ u16  hls[64 * 136];   // stage-1 h (bf16), row stride 136
  __shared__ float cls[64 * 128];  // stage-1 c (f32)
  const int w = threadIdx.x >> 6, lane = threadIdx.x & 63;
  const int quad = lane >> 4, l15 = lane & 15;
  const int hh = w * 16 + l15;
  const int m0 = blockIdx.x * 64;       // stage-1 (level l) first row
  const int M02 = blockIdx.x * 32;      // stage-2 (level l+1) first row
  const int n2 = n >> 1;

  // ---- stage-2 dep indices (hop 1 of the 2-hop chain), issued first ----
  int row2[8];
  #pragma unroll
  for (int i = 0; i < 8; ++i) {
    int m2 = M02 + (i >> 2) * 16 + quad * 4 + (i & 3);
    int j2 = m2 & (n2 - 1);
    int b2 = m2 >> (ln2n - 1);
    row2[i] = b2 * S_ + deprow2[j2];
  }

  // ---- stage-1 prefetch: dep -> xg rows ----
  ushort4 xv[16];
  #pragma unroll
  for (int i = 0; i < 16; ++i) {
    int m = m0 + (i >> 2) * 16 + quad * 4 + (i & 3);
    int j = m & (n - 1);
    int b = m >> ln2n;
    xv[i] = xg4[((size_t)b * S_ + deprow1[j]) * 128 + hh];
  }

  f32x4 acc[4][5];
  #pragma unroll
  for (int r = 0; r < 4; ++r)
    #pragma unroll
    for (int g = 0; g < 5; ++g) acc[r][g] = (f32x4){0.f, 0.f, 0.f, 0.f};

  const u16* ap = hPrev + (size_t)(m0 + l15) * 256 + quad * 8;

  #pragma unroll
  for (int s = 0; s < 8; ++s) {
    bf16x8 a[4];
    #pragma unroll
    for (int r = 0; r < 4; ++r)
      a[r] = *reinterpret_cast<const bf16x8*>(ap + (size_t)r * 16 * 256 + s * 32);
    #pragma unroll
    for (int g = 0; g < 5; ++g) {
      int t = g * 8 + w;
      bf16x8 b = *reinterpret_cast<const bf16x8*>(Bu + ((size_t)(t * 8 + s) * 64 + lane) * 8);
      #pragma unroll
      for (int r = 0; r < 4; ++r)
        acc[r][g] = __builtin_amdgcn_mfma_f32_16x16x32_bf16(a[r], b, acc[r][g], 0, 0, 0);
    }
  }

  // ---- stage-2 xg gather (hop 2), hidden under the stage-1 epilogue ----
  ushort4 xv2[8];
  #pragma unroll
  for (int i = 0; i < 8; ++i)
    xv2[i] = xg4[(size_t)row2[i] * 128 + hh];

  float bdv = bd[hh];

  // ---- stage-1 epilogue -> LDS only ----
  #pragma unroll
  for (int i = 0; i < 16; ++i) {
    int r = i >> 2, reg = i & 3;
    int m = m0 + r * 16 + quad * 4 + reg;
    int lr = m - m0;                    // local row 0..63
    ushort4 v = xv[i];
    float x0 = bf2f(v.x), x1 = bf2f(v.y), x2 = bf2f(v.z), x3 = bf2f(v.w);
    float cl = cPrev[(size_t)m * 256 + hh];
    float cr = cPrev[(size_t)m * 256 + 128 + hh];
    float pi  = acc[r][0][reg] + x0;
    float pfl = acc[r][1][reg] + x1;
    float pfr = acc[r][2][reg] + x1 + bdv;
    float po  = acc[r][3][reg] + x2;
    float pu  = acc[r][4][reg] + x3;
    float c = sigm(pi) * tanh_f(pu) + sigm(pfl) * cl + sigm(pfr) * cr;
    float h = sigm(po) * tanh_f(c);
    hls[lr * 136 + hh] = f2bf(h);
    cls[lr * 128 + hh] = c;
  }
  __syncthreads();

  // ---- stage 2: 32 rows of level l+1, A from LDS ----
  f32x4 acc2[2][5];
  #pragma unroll
  for (int r = 0; r < 2; ++r)
    #pragma unroll
    for (int g = 0; g < 5; ++g) acc2[r][g] = (f32x4){0.f, 0.f, 0.f, 0.f};

  #pragma unroll
  for (int s = 0; s < 8; ++s) {
    int child = 2 * l15 + (s >= 4 ? 1 : 0);
    int kk = (s & 3) * 32 + quad * 8;
    bf16x8 a0 = *reinterpret_cast<const bf16x8*>(&hls[child * 136 + kk]);
    bf16x8 a1 = *reinterpret_cast<const bf16x8*>(&hls[(child + 32) * 136 + kk]);
    #pragma unroll
    for (int g = 0; g < 5; ++g) {
      int t = g * 8 + w;
      bf16x8 bb = *reinterpret_cast<const bf16x8*>(Bu + ((size_t)(t * 8 + s) * 64 + lane) * 8);
      acc2[0][g] = __builtin_amdgcn_mfma_f32_16x16x32_bf16(a0, bb, acc2[0][g], 0, 0, 0);
      acc2[1][g] = __builtin_amdgcn_mfma_f32_16x16x32_bf16(a1, bb, acc2[1][g], 0, 0, 0);
    }
  }

  #pragma unroll
  for (int i = 0; i < 8; ++i) {
    int r = i >> 2, reg = i & 3;
    int m2 = M02 + r * 16 + quad * 4 + reg;
    int lj = r * 16 + quad * 4 + reg;   // local stage-2 row 0..31
    ushort4 v = xv2[i];
    float x0 = bf2f(v.x), x1 = bf2f(v.y), x2 = bf2f(v.z), x3 = bf2f(v.w);
    float cl = cls[(2 * lj) * 128 + hh];
    float cr = cls[(2 * lj + 1) * 128 + hh];
    float pi  = acc2[r][0][reg] + x0;
    float pfl = acc2[r][1][reg] + x1;
    float pfr = acc2[r][2][reg] + x1 + bdv;
    float po  = acc2[r][3][reg] + x2;
    float pu  = acc2[r][4][reg] + x3;
    float c = sigm(pi) * tanh_f(pu) + sigm(pfl) * cl + sigm(pfr) * cr;
    float h = sigm(po) * tanh_f(c);
    hOut2[(size_t)m2 * 128 + hh] = f2bf(h);
    cOut2[(size_t)m2 * 128 + hh] = c;
  }
}

// ---------------------------------------------------------------------------
// Levels 7..12 fused (R11 structure, unchanged): level 7 unrolled, 8..12 one
// small loop body with pipelined cross-level xg prefetch. One block per batch.
// ---------------------------------------------------------------------------
__global__ __launch_bounds__(512) void deep_fused(
    const ushort4* __restrict__ xg4, const int* __restrict__ dep,
    const u16* __restrict__ Bu, const float* __restrict__ bd,
    const u16* __restrict__ h6, const float* __restrict__ c6,
    float* __restrict__ out)
{
  __shared__ u16  hls[2][32 * 136];
  __shared__ float cls[2][32 * 128];
  const int b = blockIdx.x;
  const int w = threadIdx.x >> 6, lane = threadIdx.x & 63;
  const int quad = lane >> 4, l15 = lane & 15;
  const int hh = w * 16 + l15;

  const float bdv = bd[hh];

  // ================= level 7 (32 rows, global h6/c6) =================
  {
    ushort4 xv[2][4];
    float clv[2][4], crv[2][4];
    #pragma unroll
    for (int r = 0; r < 2; ++r)
      #pragma unroll
      for (int reg = 0; reg < 4; ++reg) {
        int j = r * 16 + quad * 4 + reg;
        int dj = dep[6 * 2048 + j];
        xv[r][reg] = xg4[((size_t)b * S_ + dj) * 128 + hh];
        clv[r][reg] = c6[(size_t)(b * 32 + j) * 256 + hh];
        crv[r][reg] = c6[(size_t)(b * 32 + j) * 256 + 128 + hh];
      }

    f32x4 acc[2][5];
    #pragma unroll
    for (int r = 0; r < 2; ++r)
      #pragma unroll
      for (int g = 0; g < 5; ++g) acc[r][g] = (f32x4){0.f, 0.f, 0.f, 0.f};

    #pragma unroll
    for (int s = 0; s < 8; ++s) {
      const u16* ap = h6 + (size_t)(b * 32 + l15) * 256 + s * 32 + quad * 8;
      bf16x8 a0 = *reinterpret_cast<const bf16x8*>(ap);
      bf16x8 a1 = *reinterpret_cast<const bf16x8*>(ap + 16 * 256);
      #pragma unroll
      for (int g = 0; g < 5; ++g) {
        int t = g * 8 + w;
        bf16x8 bb = *reinterpret_cast<const bf16x8*>(Bu + ((size_t)(t * 8 + s) * 64 + lane) * 8);
        acc[0][g] = __builtin_amdgcn_mfma_f32_16x16x32_bf16(a0, bb, acc[0][g], 0, 0, 0);
        acc[1][g] = __builtin_amdgcn_mfma_f32_16x16x32_bf16(a1, bb, acc[1][g], 0, 0, 0);
      }
    }

    #pragma unroll
    for (int r = 0; r < 2; ++r)
      #pragma unroll
      for (int reg = 0; reg < 4; ++reg) {
        int j = r * 16 + quad * 4 + reg;
        ushort4 v = xv[r][reg];
        float x0 = bf2f(v.x), x1 = bf2f(v.y), x2 = bf2f(v.z), x3 = bf2f(v.w);
        float pi  = acc[r][0][reg] + x0;
        float pfl = acc[r][1][reg] + x1;
        float pfr = acc[r][2][reg] + x1 + bdv;
        float po  = acc[r][3][reg] + x2;
        float pu  = acc[r][4][reg] + x3;
        float c = sigm(pi) * tanh_f(pu) + sigm(pfl) * clv[r][reg] + sigm(pfr) * crv[r][reg];
        float h = sigm(po) * tanh_f(c);
        hls[0][j * 136 + hh] = f2bf(h);
        cls[0][j * 128 + hh] = c;
      }
  }
  __syncthreads();

  // ============ levels 8..12: one shared loop body ============
  ushort4 xvc[4];
  #pragma unroll
  for (int reg = 0; reg < 4; ++reg)
    xvc[reg] = xg4[((size_t)b * S_ + dep[7 * 2048 + quad * 4 + reg]) * 128 + hh];

  int pb = 0;
  for (int lvl = 8; lvl <= 12; ++lvl) {
    int nb = 4096 >> lvl;

    ushort4 xvn[4];
    if (lvl < 12) {
      int nbn = 2048 >> lvl;
      #pragma unroll
      for (int reg = 0; reg < 4; ++reg) {
        int j = quad * 4 + reg;
        if (j < nbn)
          xvn[reg] = xg4[((size_t)b * S_ + dep[lvl * 2048 + j]) * 128 + hh];
      }
    }

    f32x4 acc[5];
    #pragma unroll
    for (int g = 0; g < 5; ++g) acc[g] = (f32x4){0.f, 0.f, 0.f, 0.f};

    #pragma unroll
    for (int s = 0; s < 8; ++s) {
      int child = 2 * l15 + (s >= 4 ? 1 : 0);
      int kk = (s & 3) * 32 + quad * 8;
      bf16x8 a = *reinterpret_cast<const bf16x8*>(&hls[pb][child * 136 + kk]);
      #pragma unroll
      for (int g = 0; g < 5; ++g) {
        int t = g * 8 + w;
        bf16x8 bb = *reinterpret_cast<const bf16x8*>(Bu + ((size_t)(t * 8 + s) * 64 + lane) * 8);
        acc[g] = __builtin_amdgcn_mfma_f32_16x16x32_bf16(a, bb, acc[g], 0, 0, 0);
      }
    }

    #pragma unroll
    for (int reg = 0; reg < 4; ++reg) {
      int j = quad * 4 + reg;
      if (j < nb) {
        ushort4 v = xvc[reg];
        float x0 = bf2f(v.x), x1 = bf2f(v.y), x2 = bf2f(v.z), x3 = bf2f(v.w);
        float cl = cls[pb][(2 * j) * 128 + hh];
        float cr = cls[pb][(2 * j + 1) * 128 + hh];
        float pi  = acc[0][reg] + x0;
        float pfl = acc[1][reg] + x1;
        float pfr = acc[2][reg] + x1 + bdv;
        float po  = acc[3][reg] + x2;
        float pu  = acc[4][reg] + x3;
        float c = sigm(pi) * tanh_f(pu) + sigm(pfl) * cl + sigm(pfr) * cr;
        float h = sigm(po) * tanh_f(c);
        hls[pb ^ 1][j * 136 + hh] = f2bf(h);
        cls[pb ^ 1][j * 128 + hh] = c;
        if (lvl == 12) {
          out[b * 128 + hh] = h;
          out[2048 + b * 128 + hh] = c;
        }
      }
    }
    __syncthreads();
    pb ^= 1;
    #pragma unroll
    for (int reg = 0; reg < 4; ++reg) xvc[reg] = xvn[reg];
  }
}

extern "C" void kernel_launch(void* const* d_in, const int* in_sizes, int n_in,
                              void* d_out, int out_size, void* d_ws, size_t ws_size,
                              hipStream_t stream)
{
  const float* emb = (const float*)d_in[0];
  const float* Wx  = (const float*)d_in[1];
  const float* bx  = (const float*)d_in[2];
  const float* Ul  = (const float*)d_in[3];
  const float* bl  = (const float*)d_in[4];
  const float* Ur  = (const float*)d_in[5];
  const float* br  = (const float*)d_in[6];
  const int* seq = (const int*)d_in[7];
  const int* dep = (const int*)d_in[8];

  char* p = (char*)d_ws;
  u16* embB = (u16*)p;    p += (size_t)V_ * 128 * 2;              // 12,800,000
  u16* BswX = (u16*)p;    p += 131072;
  u16* BswU = (u16*)p;    p += 327680;
  float* bxs = (float*)p; p += 2048;
  float* bd = (float*)p;  p += 2048;
  u16* xg = (u16*)p;      p += (size_t)B_ * S_ * 512 * 2;         // 67,108,864
  u16* h0 = (u16*)p;      p += (size_t)B_ * S_ * 128 * 2;         // 16,777,216
  float* c0 = (float*)p;  p += (size_t)B_ * S_ * 128 * 4;         // 33,554,432
  u16* hL2 = (u16*)p;     p += (size_t)16384 * 128 * 2;           // 4,194,304
  float* cL2 = (float*)p; p += (size_t)16384 * 128 * 4;           // 16,777,216
  u16* hL4 = (u16*)p;     p += (size_t)4096 * 128 * 2;            // 1,048,576
  float* cL4 = (float*)p; p += (size_t)4096 * 128 * 4;            // 2,097,152
  u16* hL6 = (u16*)p;     p += (size_t)1024 * 128 * 2;            // 262,144
  float* cL6 = (float*)p; p += (size_t)1024 * 128 * 4;            // 524,288

  const int prep_tot = PREP_N0 + PREP_N1 + PREP_N2 + PREP_N3;
  prep_all<<<dim3((prep_tot + 255) / 256), dim3(256), 0, stream>>>(
      emb, Wx, Ul, Ur, bl, br, bx, embB, BswX, BswU, bxs, bd);

  xg_mfma<<<dim3(B_ * S_ / 32), dim3(512), 0, stream>>>(
      embB, BswX, bxs, seq, (ushort4*)xg, h0, c0);

  const ushort4* xg4 = (const ushort4*)xg;

  // pair (1,2): 32768 stage-1 rows -> 512 blocks
  level_pair<<<dim3(512), dim3(512), 0, stream>>>(
      xg4, dep, dep + 2048, BswU, bd, h0, c0, hL2, cL2, 2048, 11);
  // pair (3,4): 8192 stage-1 rows -> 128 blocks
  level_pair<<<dim3(128), dim3(512), 0, stream>>>(
      xg4, dep + 2 * 2048, dep + 3 * 2048, BswU, bd, hL2, cL2, hL4, cL4, 512, 9);
  // pair (5,6): 2048 stage-1 rows -> 32 blocks
  level_pair<<<dim3(32), dim3(512), 0, stream>>>(
      xg4, dep + 4 * 2048, dep + 5 * 2048, BswU, bd, hL4, cL4, hL6, cL6, 128, 7);

  // levels 7..12 fused per batch.
  deep_fused<<<dim3(16), dim3(512), 0, stream>>>(
      xg4, dep, BswU, bd, hL6, cL6, (float*)d_out);
}

// Round 15
// 264.781 us; speedup vs baseline: 1.0671x; 1.0671x over previous
//
#include <hip/hip_runtime.h>
#include <hip/hip_bf16.h>

#define V_ 50000
#define E_ 100
#define H_ 128
#define B_ 16
#define S_ 4096

typedef unsigned short u16;
typedef unsigned int   u32;
typedef short bf16x8 __attribute__((ext_vector_type(8)));  // 8 bf16 = 4 VGPRs
typedef float f32x4  __attribute__((ext_vector_type(4)));

__device__ __forceinline__ float bf2f(u16 x) {
  return __uint_as_float(((u32)x) << 16);
}
__device__ __forceinline__ u16 f2bf(float x) {
  __hip_bfloat16 b = __float2bfloat16(x);
  return *reinterpret_cast<u16*>(&b);
}
__device__ __forceinline__ float sigm(float x) { return 1.0f / (1.0f + __expf(-x)); }
__device__ __forceinline__ float tanh_f(float x) {
  float e = __expf(2.0f * x);
  return 1.0f - 2.0f / (e + 1.0f);
}

// ---------------------------------------------------------------------------
// Merged prep: embB bf16, W_x/Ucat B-frag swizzles, bxs = bx+bl+br (per XMAP),
// bd = f_r - f_l bias delta.
// ---------------------------------------------------------------------------
#define PREP_N0 (V_ * 128)
#define PREP_N1 65536
#define PREP_N2 163840
#define PREP_N3 640
__global__ __launch_bounds__(256) void prep_all(
    const float* __restrict__ emb, const float* __restrict__ Wx,
    const float* __restrict__ Ul, const float* __restrict__ Ur,
    const float* __restrict__ bl, const float* __restrict__ br,
    const float* __restrict__ bx,
    u16* __restrict__ embB, u16* __restrict__ Bx, u16* __restrict__ Bu,
    float* __restrict__ bxs, float* __restrict__ bd)
{
  int i = blockIdx.x * 256 + threadIdx.x;
  if (i < PREP_N0) {
    int k = i & 127, t = i >> 7;
    embB[i] = (k < E_) ? f2bf(emb[t * E_ + k]) : (u16)0;
    return;
  }
  i -= PREP_N0;
  if (i < PREP_N1) {
    int j = i & 7, l = (i >> 3) & 63, s = (i >> 9) & 3, t = i >> 11;
    int k = s * 32 + (l >> 4) * 8 + j;
    int o = t * 16 + (l & 15);
    Bx[i] = (k < E_) ? f2bf(Wx[o * E_ + k]) : (u16)0;
    return;
  }
  i -= PREP_N1;
  if (i < PREP_N2) {
    int j = i & 7, l = (i >> 3) & 63, s = (i >> 9) & 7, t = i >> 12;
    int k = s * 32 + (l >> 4) * 8 + j;
    int gh = t * 16 + (l & 15);
    float v = (k < 128) ? Ul[gh * 128 + k] : Ur[gh * 128 + (k - 128)];
    Bu[i] = f2bf(v);
    return;
  }
  i -= PREP_N2;
  if (i < 512) {
    int g = i >> 7, hh = i & 127;
    int lg = (g == 0) ? 0 : (g == 1) ? 1 : (g == 2) ? 3 : 4;
    bxs[i] = bx[i] + bl[lg * 128 + hh] + br[lg * 128 + hh];
    return;
  }
  i -= 512;
  if (i < 128) bd[i] = (bl[256 + i] + br[256 + i]) - (bl[128 + i] + br[128 + i]);
}

// ---------------------------------------------------------------------------
// xg GEMM via MFMA + LDS transpose (XLDS=514: conflict-free). Biases folded.
// Epilogue emits level-0 h (bf16) and c0 (bf16), once per element.
// ---------------------------------------------------------------------------
#define XLDS 514
__global__ __launch_bounds__(512) void xg_mfma(
    const u16* __restrict__ embB, const u16* __restrict__ Bx,
    const float* __restrict__ bxs, const int* __restrict__ seq,
    ushort4* __restrict__ xg, u16* __restrict__ h0, u16* __restrict__ c0)
{
  __shared__ u16 lds[32 * XLDS];
  const int w = threadIdx.x >> 6, lane = threadIdx.x & 63;
  const int quad = lane >> 4, l15 = lane & 15;
  const int m0 = blockIdx.x * 32;

  f32x4 acc[2][4];
  #pragma unroll
  for (int r = 0; r < 2; ++r)
    #pragma unroll
    for (int t = 0; t < 4; ++t) acc[r][t] = (f32x4){0.f, 0.f, 0.f, 0.f};

  int tok0 = seq[m0 + l15];
  int tok1 = seq[m0 + 16 + l15];
  const u16* a0p = embB + (size_t)tok0 * 128 + quad * 8;
  const u16* a1p = embB + (size_t)tok1 * 128 + quad * 8;

  #pragma unroll
  for (int s = 0; s < 4; ++s) {
    bf16x8 a0 = *reinterpret_cast<const bf16x8*>(a0p + s * 32);
    bf16x8 a1 = *reinterpret_cast<const bf16x8*>(a1p + s * 32);
    #pragma unroll
    for (int ti = 0; ti < 4; ++ti) {
      int t = w * 4 + ti;
      bf16x8 b = *reinterpret_cast<const bf16x8*>(Bx + ((size_t)(t * 4 + s) * 64 + lane) * 8);
      acc[0][ti] = __builtin_amdgcn_mfma_f32_16x16x32_bf16(a0, b, acc[0][ti], 0, 0, 0);
      acc[1][ti] = __builtin_amdgcn_mfma_f32_16x16x32_bf16(a1, b, acc[1][ti], 0, 0, 0);
    }
  }

  const int g = w >> 1;
  #pragma unroll
  for (int ti = 0; ti < 4; ++ti) {
    int o = (w * 4 + ti) * 16 + l15;
    float bxo = bxs[o];
    int hhw = (w & 1) * 64 + ti * 16 + l15;
    #pragma unroll
    for (int r = 0; r < 2; ++r)
      #pragma unroll
      for (int reg = 0; reg < 4; ++reg) {
        int mrow = r * 16 + quad * 4 + reg;
        lds[mrow * XLDS + hhw * 4 + g] = f2bf(acc[r][ti][reg] + bxo);
      }
  }
  __syncthreads();

  #pragma unroll
  for (int i = 0; i < 8; ++i) {
    int pidx = i * 512 + threadIdx.x;
    int m = pidx >> 7, hh = pidx & 127;
    ushort4 v = *reinterpret_cast<const ushort4*>(&lds[m * XLDS + hh * 4]);
    size_t gm = (size_t)(m0 + m);
    xg[gm * 128 + hh] = v;
    float c = sigm(bf2f(v.x)) * tanh_f(bf2f(v.w));
    float h = sigm(bf2f(v.z)) * tanh_f(c);
    h0[gm * 128 + hh] = f2bf(h);
    c0[gm * 128 + hh] = f2bf(c);
  }
}

// ---------------------------------------------------------------------------
// Levels 1..3 via MFMA, Mtile=64, no register cap. c in bf16.
// ---------------------------------------------------------------------------
__global__ __launch_bounds__(512) void level_mfma64(
    const ushort4* __restrict__ xg4, const int* __restrict__ deprow,
    const u16* __restrict__ Bu, const float* __restrict__ bd,
    const u16* __restrict__ hPrev, const u16* __restrict__ cPrev,
    u16* __restrict__ hOut, u16* __restrict__ cOut, int n, int ln2n)
{
  const int w = threadIdx.x >> 6, lane = threadIdx.x & 63;
  const int quad = lane >> 4, l15 = lane & 15;
  const int hh = w * 16 + l15;
  const int m0 = blockIdx.x * 64;

  ushort4 xv[16];
  #pragma unroll
  for (int i = 0; i < 16; ++i) {
    int m = m0 + (i >> 2) * 16 + quad * 4 + (i & 3);
    int j = m & (n - 1);
    int b = m >> ln2n;
    xv[i] = xg4[((size_t)b * S_ + deprow[j]) * 128 + hh];
  }

  f32x4 acc[4][5];
  #pragma unroll
  for (int r = 0; r < 4; ++r)
    #pragma unroll
    for (int g = 0; g < 5; ++g) acc[r][g] = (f32x4){0.f, 0.f, 0.f, 0.f};

  const u16* ap = hPrev + (size_t)(m0 + l15) * 256 + quad * 8;

  #pragma unroll
  for (int s = 0; s < 8; ++s) {
    bf16x8 a[4];
    #pragma unroll
    for (int r = 0; r < 4; ++r)
      a[r] = *reinterpret_cast<const bf16x8*>(ap + (size_t)r * 16 * 256 + s * 32);
    #pragma unroll
    for (int g = 0; g < 5; ++g) {
      int t = g * 8 + w;
      bf16x8 b = *reinterpret_cast<const bf16x8*>(Bu + ((size_t)(t * 8 + s) * 64 + lane) * 8);
      #pragma unroll
      for (int r = 0; r < 4; ++r)
        acc[r][g] = __builtin_amdgcn_mfma_f32_16x16x32_bf16(a[r], b, acc[r][g], 0, 0, 0);
    }
  }

  float bdv = bd[hh];
  #pragma unroll
  for (int i = 0; i < 16; ++i) {
    int r = i >> 2, reg = i & 3;
    int m = m0 + r * 16 + quad * 4 + reg;
    ushort4 v = xv[i];
    float x0 = bf2f(v.x), x1 = bf2f(v.y), x2 = bf2f(v.z), x3 = bf2f(v.w);
    float cl = bf2f(cPrev[(size_t)m * 256 + hh]);
    float cr = bf2f(cPrev[(size_t)m * 256 + 128 + hh]);
    float pi  = acc[r][0][reg] + x0;
    float pfl = acc[r][1][reg] + x1;
    float pfr = acc[r][2][reg] + x1 + bdv;
    float po  = acc[r][3][reg] + x2;
    float pu  = acc[r][4][reg] + x3;
    float c = sigm(pi) * tanh_f(pu) + sigm(pfl) * cl + sigm(pfr) * cr;
    float h = sigm(po) * tanh_f(c);
    hOut[(size_t)m * 128 + hh] = f2bf(h);
    cOut[(size_t)m * 128 + hh] = f2bf(c);
  }
}

// ---------------------------------------------------------------------------
// Levels 4..6 via MFMA, Mtile=32. c in bf16.
// ---------------------------------------------------------------------------
__global__ __launch_bounds__(512) void level_mfma(
    const ushort4* __restrict__ xg4, const int* __restrict__ deprow,
    const u16* __restrict__ Bu, const float* __restrict__ bd,
    const u16* __restrict__ hPrev, const u16* __restrict__ cPrev,
    u16* __restrict__ hOut, u16* __restrict__ cOut, int n, int ln2n)
{
  const int w = threadIdx.x >> 6, lane = threadIdx.x & 63;
  const int quad = lane >> 4, l15 = lane & 15;
  const int hh = w * 16 + l15;
  const int m0 = blockIdx.x * 32;

  ushort4 xv[8];
  float clv[8], crv[8];
  #pragma unroll
  for (int i = 0; i < 8; ++i) {
    int m = m0 + (i >> 2) * 16 + quad * 4 + (i & 3);
    int j = m & (n - 1);
    int b = m >> ln2n;
    int dj = deprow[j];
    xv[i] = xg4[((size_t)b * S_ + dj) * 128 + hh];
    clv[i] = bf2f(cPrev[(size_t)m * 256 + hh]);
    crv[i] = bf2f(cPrev[(size_t)m * 256 + 128 + hh]);
  }

  f32x4 acc[2][5];
  #pragma unroll
  for (int r = 0; r < 2; ++r)
    #pragma unroll
    for (int g = 0; g < 5; ++g) acc[r][g] = (f32x4){0.f, 0.f, 0.f, 0.f};

  const u16* a0p = hPrev + (size_t)(m0 + l15) * 256 + quad * 8;
  const u16* a1p = a0p + 16 * 256;

  #pragma unroll
  for (int s = 0; s < 8; ++s) {
    bf16x8 a0 = *reinterpret_cast<const bf16x8*>(a0p + s * 32);
    bf16x8 a1 = *reinterpret_cast<const bf16x8*>(a1p + s * 32);
    #pragma unroll
    for (int g = 0; g < 5; ++g) {
      int t = g * 8 + w;
      bf16x8 b = *reinterpret_cast<const bf16x8*>(Bu + ((size_t)(t * 8 + s) * 64 + lane) * 8);
      acc[0][g] = __builtin_amdgcn_mfma_f32_16x16x32_bf16(a0, b, acc[0][g], 0, 0, 0);
      acc[1][g] = __builtin_amdgcn_mfma_f32_16x16x32_bf16(a1, b, acc[1][g], 0, 0, 0);
    }
  }

  float bdv = bd[hh];
  #pragma unroll
  for (int i = 0; i < 8; ++i) {
    int r = i >> 2, reg = i & 3;
    int m = m0 + r * 16 + quad * 4 + reg;
    ushort4 v = xv[i];
    float x0 = bf2f(v.x), x1 = bf2f(v.y), x2 = bf2f(v.z), x3 = bf2f(v.w);
    float pi  = acc[r][0][reg] + x0;
    float pfl = acc[r][1][reg] + x1;
    float pfr = acc[r][2][reg] + x1 + bdv;
    float po  = acc[r][3][reg] + x2;
    float pu  = acc[r][4][reg] + x3;
    float c = sigm(pi) * tanh_f(pu) + sigm(pfl) * clv[i] + sigm(pfr) * crv[i];
    float h = sigm(po) * tanh_f(c);
    hOut[(size_t)m * 128 + hh] = f2bf(h);
    cOut[(size_t)m * 128 + hh] = f2bf(c);
  }
}

// ---------------------------------------------------------------------------
// Levels 7..12 fused (R11 structure): level 7 unrolled, 8..12 one small loop
// body with pipelined cross-level xg prefetch. One block per batch. c6 bf16.
// ---------------------------------------------------------------------------
__global__ __launch_bounds__(512) void deep_fused(
    const ushort4* __restrict__ xg4, const int* __restrict__ dep,
    const u16* __restrict__ Bu, const float* __restrict__ bd,
    const u16* __restrict__ h6, const u16* __restrict__ c6,
    float* __restrict__ out)
{
  __shared__ u16  hls[2][32 * 136];
  __shared__ float cls[2][32 * 128];
  const int b = blockIdx.x;
  const int w = threadIdx.x >> 6, lane = threadIdx.x & 63;
  const int quad = lane >> 4, l15 = lane & 15;
  const int hh = w * 16 + l15;

  const float bdv = bd[hh];

  // ================= level 7 (32 rows, global h6/c6) =================
  {
    ushort4 xv[2][4];
    float clv[2][4], crv[2][4];
    #pragma unroll
    for (int r = 0; r < 2; ++r)
      #pragma unroll
      for (int reg = 0; reg < 4; ++reg) {
        int j = r * 16 + quad * 4 + reg;
        int dj = dep[6 * 2048 + j];
        xv[r][reg] = xg4[((size_t)b * S_ + dj) * 128 + hh];
        clv[r][reg] = bf2f(c6[(size_t)(b * 32 + j) * 256 + hh]);
        crv[r][reg] = bf2f(c6[(size_t)(b * 32 + j) * 256 + 128 + hh]);
      }

    f32x4 acc[2][5];
    #pragma unroll
    for (int r = 0; r < 2; ++r)
      #pragma unroll
      for (int g = 0; g < 5; ++g) acc[r][g] = (f32x4){0.f, 0.f, 0.f, 0.f};

    #pragma unroll
    for (int s = 0; s < 8; ++s) {
      const u16* ap = h6 + (size_t)(b * 32 + l15) * 256 + s * 32 + quad * 8;
      bf16x8 a0 = *reinterpret_cast<const bf16x8*>(ap);
      bf16x8 a1 = *reinterpret_cast<const bf16x8*>(ap + 16 * 256);
      #pragma unroll
      for (int g = 0; g < 5; ++g) {
        int t = g * 8 + w;
        bf16x8 bb = *reinterpret_cast<const bf16x8*>(Bu + ((size_t)(t * 8 + s) * 64 + lane) * 8);
        acc[0][g] = __builtin_amdgcn_mfma_f32_16x16x32_bf16(a0, bb, acc[0][g], 0, 0, 0);
        acc[1][g] = __builtin_amdgcn_mfma_f32_16x16x32_bf16(a1, bb, acc[1][g], 0, 0, 0);
      }
    }

    #pragma unroll
    for (int r = 0; r < 2; ++r)
      #pragma unroll
      for (int reg = 0; reg < 4; ++reg) {
        int j = r * 16 + quad * 4 + reg;
        ushort4 v = xv[r][reg];
        float x0 = bf2f(v.x), x1 = bf2f(v.y), x2 = bf2f(v.z), x3 = bf2f(v.w);
        float pi  = acc[r][0][reg] + x0;
        float pfl = acc[r][1][reg] + x1;
        float pfr = acc[r][2][reg] + x1 + bdv;
        float po  = acc[r][3][reg] + x2;
        float pu  = acc[r][4][reg] + x3;
        float c = sigm(pi) * tanh_f(pu) + sigm(pfl) * clv[r][reg] + sigm(pfr) * crv[r][reg];
        float h = sigm(po) * tanh_f(c);
        hls[0][j * 136 + hh] = f2bf(h);
        cls[0][j * 128 + hh] = c;
      }
  }
  __syncthreads();

  // ============ levels 8..12: one shared loop body ============
  ushort4 xvc[4];
  #pragma unroll
  for (int reg = 0; reg < 4; ++reg)
    xvc[reg] = xg4[((size_t)b * S_ + dep[7 * 2048 + quad * 4 + reg]) * 128 + hh];

  int pb = 0;
  for (int lvl = 8; lvl <= 12; ++lvl) {
    int nb = 4096 >> lvl;

    ushort4 xvn[4];
    if (lvl < 12) {
      int nbn = 2048 >> lvl;
      #pragma unroll
      for (int reg = 0; reg < 4; ++reg) {
        int j = quad * 4 + reg;
        if (j < nbn)
          xvn[reg] = xg4[((size_t)b * S_ + dep[lvl * 2048 + j]) * 128 + hh];
      }
    }

    f32x4 acc[5];
    #pragma unroll
    for (int g = 0; g < 5; ++g) acc[g] = (f32x4){0.f, 0.f, 0.f, 0.f};

    #pragma unroll
    for (int s = 0; s < 8; ++s) {
      int child = 2 * l15 + (s >= 4 ? 1 : 0);
      int kk = (s & 3) * 32 + quad * 8;
      bf16x8 a = *reinterpret_cast<const bf16x8*>(&hls[pb][child * 136 + kk]);
      #pragma unroll
      for (int g = 0; g < 5; ++g) {
        int t = g * 8 + w;
        bf16x8 bb = *reinterpret_cast<const bf16x8*>(Bu + ((size_t)(t * 8 + s) * 64 + lane) * 8);
        acc[g] = __builtin_amdgcn_mfma_f32_16x16x32_bf16(a, bb, acc[g], 0, 0, 0);
      }
    }

    #pragma unroll
    for (int reg = 0; reg < 4; ++reg) {
      int j = quad * 4 + reg;
      if (j < nb) {
        ushort4 v = xvc[reg];
        float x0 = bf2f(v.x), x1 = bf2f(v.y), x2 = bf2f(v.z), x3 = bf2f(v.w);
        float cl = cls[pb][(2 * j) * 128 + hh];
        float cr = cls[pb][(2 * j + 1) * 128 + hh];
        float pi  = acc[0][reg] + x0;
        float pfl = acc[1][reg] + x1;
        float pfr = acc[2][reg] + x1 + bdv;
        float po  = acc[3][reg] + x2;
        float pu  = acc[4][reg] + x3;
        float c = sigm(pi) * tanh_f(pu) + sigm(pfl) * cl + sigm(pfr) * cr;
        float h = sigm(po) * tanh_f(c);
        hls[pb ^ 1][j * 136 + hh] = f2bf(h);
        cls[pb ^ 1][j * 128 + hh] = c;
        if (lvl == 12) {
          out[b * 128 + hh] = h;
          out[2048 + b * 128 + hh] = c;
        }
      }
    }
    __syncthreads();
    pb ^= 1;
    #pragma unroll
    for (int reg = 0; reg < 4; ++reg) xvc[reg] = xvn[reg];
  }
}

extern "C" void kernel_launch(void* const* d_in, const int* in_sizes, int n_in,
                              void* d_out, int out_size, void* d_ws, size_t ws_size,
                              hipStream_t stream)
{
  const float* emb = (const float*)d_in[0];
  const float* Wx  = (const float*)d_in[1];
  const float* bx  = (const float*)d_in[2];
  const float* Ul  = (const float*)d_in[3];
  const float* bl  = (const float*)d_in[4];
  const float* Ur  = (const float*)d_in[5];
  const float* br  = (const float*)d_in[6];
  const int* seq = (const int*)d_in[7];
  const int* dep = (const int*)d_in[8];

  char* p = (char*)d_ws;
  u16* embB = (u16*)p;    p += (size_t)V_ * 128 * 2;              // 12,800,000
  u16* BswX = (u16*)p;    p += 131072;
  u16* BswU = (u16*)p;    p += 327680;
  float* bxs = (float*)p; p += 2048;
  float* bd = (float*)p;  p += 2048;
  u16* xg = (u16*)p;      p += (size_t)B_ * S_ * 512 * 2;         // 67,108,864
  u16* h0 = (u16*)p;      p += (size_t)B_ * S_ * 128 * 2;         // 16,777,216
  u16* c0 = (u16*)p;      p += (size_t)B_ * S_ * 128 * 2;         // 16,777,216
  u16* hA = (u16*)p;      p += (size_t)32768 * 128 * 2;           // 8,388,608
  u16* cA = (u16*)p;      p += (size_t)32768 * 128 * 2;           // 8,388,608
  u16* hB = (u16*)p;      p += (size_t)16384 * 128 * 2;           // 4,194,304
  u16* cB = (u16*)p;      p += (size_t)16384 * 128 * 2;           // 4,194,304

  const int prep_tot = PREP_N0 + PREP_N1 + PREP_N2 + PREP_N3;
  prep_all<<<dim3((prep_tot + 255) / 256), dim3(256), 0, stream>>>(
      emb, Wx, Ul, Ur, bl, br, bx, embB, BswX, BswU, bxs, bd);

  xg_mfma<<<dim3(B_ * S_ / 32), dim3(512), 0, stream>>>(
      embB, BswX, bxs, seq, (ushort4*)xg, h0, c0);

  const ushort4* xg4 = (const ushort4*)xg;

  // level 1: A/c from h0/c0 (32768 rows)
  level_mfma64<<<dim3(32768 / 64), dim3(512), 0, stream>>>(
      xg4, dep, BswU, bd, h0, c0, hA, cA, 2048, 11);

  u16 *hp = hA, *ho = hB;
  u16 *cp = cA, *co = cB;
  for (int l = 2; l <= 3; ++l) {
    int n = S_ >> l;
    int Mtot = B_ * n;
    const int* deprow = dep + (size_t)(l - 1) * (S_ / 2);
    level_mfma64<<<dim3(Mtot / 64), dim3(512), 0, stream>>>(
        xg4, deprow, BswU, bd, hp, cp, ho, co, n, 12 - l);
    u16* th = hp; hp = ho; ho = th;
    u16* tc = cp; cp = co; co = tc;
  }
  for (int l = 4; l <= 6; ++l) {
    int n = S_ >> l;
    int Mtot = B_ * n;
    const int* deprow = dep + (size_t)(l - 1) * (S_ / 2);
    level_mfma<<<dim3(Mtot / 32), dim3(512), 0, stream>>>(
        xg4, deprow, BswU, bd, hp, cp, ho, co, n, 12 - l);
    u16* th = hp; hp = ho; ho = th;
    u16* tc = cp; cp = co; co = tc;
  }

  // hp/cp hold level-6 output (1024 rows); levels 7..12 fused per batch.
  deep_fused<<<dim3(16), dim3(512), 0, stream>>>(
      xg4, dep, BswU, bd, hp, cp, (float*)d_out);
}